// Round 5
// baseline (105.047 us; speedup 1.0000x reference)
//
#include <hip/hip_runtime.h>

typedef __attribute__((ext_vector_type(4))) float f32x4;
typedef __attribute__((ext_vector_type(4))) int   i32x4;
typedef __attribute__((ext_vector_type(8))) short s16x8;

__device__ __forceinline__ unsigned short f2bf_rn(float f) {
  union { float f; unsigned u; } v; v.f = f;
  unsigned r = v.u + 0x7fffu + ((v.u >> 16) & 1u);
  return (unsigned short)(r >> 16);
}

// pack two fp32 -> two bf16 (round-half-up) in one int via v_perm_b32
__device__ __forceinline__ int packbf2(float lo, float hi) {
  union { float f; unsigned u; } a, b; a.f = lo; b.f = hi;
  return (int)__builtin_amdgcn_perm(b.u + 0x8000u, a.u + 0x8000u, 0x07060302u);
}

// unpack 8 bf16 (i32x4) and accumulate g*x into s0(ch0..3), s1(ch4..7)
__device__ __forceinline__ void add8(i32x4 v, float g, f32x4& s0, f32x4& s1) {
  union { int ii; float ff; } u;
  u.ii = v[0] << 16;                  s0[0] = fmaf(g, u.ff, s0[0]);
  u.ii = v[0] & (int)0xffff0000u;     s0[1] = fmaf(g, u.ff, s0[1]);
  u.ii = v[1] << 16;                  s0[2] = fmaf(g, u.ff, s0[2]);
  u.ii = v[1] & (int)0xffff0000u;     s0[3] = fmaf(g, u.ff, s0[3]);
  u.ii = v[2] << 16;                  s1[0] = fmaf(g, u.ff, s1[0]);
  u.ii = v[2] & (int)0xffff0000u;     s1[1] = fmaf(g, u.ff, s1[1]);
  u.ii = v[3] << 16;                  s1[2] = fmaf(g, u.ff, s1[2]);
  u.ii = v[3] & (int)0xffff0000u;     s1[3] = fmaf(g, u.ff, s1[3]);
}

__device__ __forceinline__ void axis_cw(float p, int& il, int& ir, float& gl, float& gr) {
  float fl = floorf(p);
  float ql = fminf(fmaxf(fl, 0.f), 193.f);
  float qr = fminf(fmaxf(fl + 1.f, 0.f), 193.f);
  float pc = fminf(fmaxf(p, 0.f), 193.f);
  gl = 1.f + (ql - pc);
  gr = 1.f - (qr - pc);
  il = (int)ql; ir = (int)qr;
}

// K0 merged: NCHW fp32 -> zero-padded bf16 NHWC xp, plus conv_w -> B-fragments.
__global__ __launch_bounds__(256) void k_prep(const float* __restrict__ x,
                                              unsigned short* __restrict__ xp,
                                              const float* __restrict__ w,
                                              short* __restrict__ wf) {
  int t = blockIdx.x * 256 + threadIdx.x;
  if (t < 2 * 194 * 194 * 4) {
    int pix = t >> 2, c8 = t & 3;
    int b = pix / (194 * 194);
    int r = pix % (194 * 194);
    int i = r / 194 - 1, j = r % 194 - 1;
    bool ok = ((unsigned)i < 192u) && ((unsigned)j < 192u);
    const float* src = x + (size_t)b * 32 * 36864 + (size_t)(c8 * 8) * 36864 + i * 192 + j;
    unsigned v[8];
    #pragma unroll
    for (int k = 0; k < 8; k++) v[k] = ok ? (unsigned)f2bf_rn(src[k * 36864]) : 0u;
    i32x4 pv;
    pv[0] = (int)(v[0] | (v[1] << 16));
    pv[1] = (int)(v[2] | (v[3] << 16));
    pv[2] = (int)(v[4] | (v[5] << 16));
    pv[3] = (int)(v[6] | (v[7] << 16));
    *(i32x4*)(xp + (size_t)pix * 32 + c8 * 8) = pv;
  } else {
    int u = t - 2 * 194 * 194 * 4;
    if (u >= 9 * 4 * 64) return;
    int n = u / 256;
    int ot = (u / 64) % 4;
    int lane = u % 64;
    int o = ot * 16 + (lane & 15);
    int cb = (lane >> 4) * 8;
    #pragma unroll
    for (int jj = 0; jj < 8; jj++) {
      float v = w[(o * 32 + cb + jj) * 9 + n];
      wf[(size_t)u * 8 + jj] = (short)f2bf_rn(v);
    }
  }
}

// K1: fused A-map + bilinear sampling + MFMA.
// o-split TLP: each wave = 16 pixels x 32 outputs (2 MFMAs/step); wave pairs
// share a segment (same L1/L2 lines). 9216 waves -> ~32 resident/CU.
__global__ __launch_bounds__(256) void k_main(const unsigned short* __restrict__ xp,
                                              const float* __restrict__ p1w,
                                              const float* __restrict__ p1b,
                                              const s16x8* __restrict__ wfv,
                                              float* __restrict__ out) {
  __shared__ float wlds[288];  // reordered p1w: wlds[tap*32 + c]
  for (int idx = threadIdx.x; idx < 288; idx += 256) {
    int c = idx / 9, tap = idx % 9;
    wlds[tap * 32 + c] = p1w[idx];
  }
  __syncthreads();

  int lane = threadIdx.x & 63;
  // XCD swizzle: 2304 blocks = 8 XCDs x 288 contiguous.
  int bs = (blockIdx.x & 7) * 288 + (blockIdx.x >> 3);
  int W2 = bs * 4 + (threadIdx.x >> 6);
  int seg = W2 >> 1;        // 0..4607
  int oh  = W2 & 1;         // o-half: 0 -> o[0,32), 1 -> o[32,64)
  int b = seg / 2304;
  int r = seg % 2304;
  int i = r / 12;
  int j0 = (r % 12) * 16;
  int m = lane & 15, quad = lane >> 4;
  int j = j0 + m;
  const unsigned short* xpb = xp + (size_t)b * (194 * 194 * 32) + quad * 8;

  // ---- inline A: 3x3x32 conv; 4 independent chains; quads split channels.
  float a0 = 0.f, a1 = 0.f, a2 = 0.f, a3 = 0.f;
  i32x4 vcen;
  #pragma unroll
  for (int tap = 0; tap < 9; tap++) {
    int kh = tap / 3, kw = tap % 3;
    i32x4 v = *(const i32x4*)(xpb + ((i + kh) * 194 + (j + kw)) * 32);
    if (tap == 4) vcen = v;
    const f32x4* wp = (const f32x4*)(wlds + tap * 32 + quad * 8);
    f32x4 w0 = wp[0], w1 = wp[1];
    union { int ii; float ff; } u;
    u.ii = v[0] << 16;              a0 = fmaf(u.ff, w0[0], a0);
    u.ii = v[0] & (int)0xffff0000u; a1 = fmaf(u.ff, w0[1], a1);
    u.ii = v[1] << 16;              a2 = fmaf(u.ff, w0[2], a2);
    u.ii = v[1] & (int)0xffff0000u; a3 = fmaf(u.ff, w0[3], a3);
    u.ii = v[2] << 16;              a0 = fmaf(u.ff, w1[0], a0);
    u.ii = v[2] & (int)0xffff0000u; a1 = fmaf(u.ff, w1[1], a1);
    u.ii = v[3] << 16;              a2 = fmaf(u.ff, w1[2], a2);
    u.ii = v[3] & (int)0xffff0000u; a3 = fmaf(u.ff, w1[3], a3);
  }
  float a = (a0 + a1) + (a2 + a3);
  a += __shfl_xor(a, 16);
  a += __shfl_xor(a, 32);
  float A = a + p1b[0];

  f32x4 acc0 = {0.f, 0.f, 0.f, 0.f};
  f32x4 acc1 = acc0;
  float cx = (float)(i + 1), cy = (float)(j + 1);
  int icx = i + 1, icy = j + 1;
  const int wofs = oh * 128;  // otiles {0,1} or {2,3}

#define DO_MFMA(n, af)                                                            \
  { int wb = (n) * 256 + lane + wofs;                                             \
    acc0 = __builtin_amdgcn_mfma_f32_16x16x32_bf16(af, wfv[wb],      acc0, 0, 0, 0); \
    acc1 = __builtin_amdgcn_mfma_f32_16x16x32_bf16(af, wfv[wb + 64], acc1, 0, 0, 0); }

  #pragma unroll
  for (int n = 0; n < 9; n++) {
    const int dx = n / 3 - 1, dy = n % 3 - 1;
    s16x8 af; int* ai = (int*)&af;
    if (dx == 0 && dy == 0) {
      ai[0] = vcen[0]; ai[1] = vcen[1]; ai[2] = vcen[2]; ai[3] = vcen[3];
    } else if (dy == 0 || dx == 0) {
      int il, ir; float gl, gr;
      if (dy == 0) axis_cw(cx + A * (float)dx, il, ir, gl, gr);
      else         axis_cw(cy + A * (float)dy, il, ir, gl, gr);
      int o_l = (dy == 0) ? (il * 194 + icy) * 32 : (icx * 194 + il) * 32;
      int o_r = (dy == 0) ? (ir * 194 + icy) * 32 : (icx * 194 + ir) * 32;
      i32x4 vl = *(const i32x4*)(xpb + o_l);
      i32x4 vr = *(const i32x4*)(xpb + o_r);
      f32x4 s0 = {0.f, 0.f, 0.f, 0.f}, s1 = s0;
      add8(vl, gl, s0, s1);
      add8(vr, gr, s0, s1);
      ai[0] = packbf2(s0[0], s0[1]); ai[1] = packbf2(s0[2], s0[3]);
      ai[2] = packbf2(s1[0], s1[1]); ai[3] = packbf2(s1[2], s1[3]);
    } else {
      int ilx, irx, ily, iry; float gxl, gxr, gyl, gyr;
      axis_cw(cx + A * (float)dx, ilx, irx, gxl, gxr);
      axis_cw(cy + A * (float)dy, ily, iry, gyl, gyr);
      i32x4 vlt = *(const i32x4*)(xpb + (ilx * 194 + ily) * 32);
      i32x4 vrb = *(const i32x4*)(xpb + (irx * 194 + iry) * 32);
      i32x4 vlb = *(const i32x4*)(xpb + (ilx * 194 + iry) * 32);
      i32x4 vrt = *(const i32x4*)(xpb + (irx * 194 + ily) * 32);
      f32x4 s0 = {0.f, 0.f, 0.f, 0.f}, s1 = s0;
      add8(vlt, gxl * gyl, s0, s1);
      add8(vrb, gxr * gyr, s0, s1);
      add8(vlb, gxl * gyr, s0, s1);
      add8(vrt, gxr * gyl, s0, s1);
      ai[0] = packbf2(s0[0], s0[1]); ai[1] = packbf2(s0[2], s0[3]);
      ai[2] = packbf2(s1[0], s1[1]); ai[3] = packbf2(s1[2], s1[3]);
    }
    DO_MFMA(n, af)
  }
#undef DO_MFMA

  // D layout: row(pixel) = quad*4 + reg, col(o) = lane&15
  int o0 = oh * 32 + (lane & 15);
  int jout = j0 + quad * 4;
  float* op = out + (size_t)b * 64 * 36864 + (size_t)o0 * 36864 + i * 192 + jout;
  *(f32x4*)(op) = acc0;
  *(f32x4*)(op + 16 * 36864) = acc1;
}

extern "C" void kernel_launch(void* const* d_in, const int* in_sizes, int n_in,
                              void* d_out, int out_size, void* d_ws, size_t ws_size,
                              hipStream_t stream) {
  const float* x      = (const float*)d_in[0];
  const float* conv_w = (const float*)d_in[1];
  const float* p1w    = (const float*)d_in[4];
  const float* p1b    = (const float*)d_in[5];
  float* out = (float*)d_out;

  unsigned short* xp = (unsigned short*)d_ws;     // 2*194*194*32 bf16
  short* wf = (short*)(xp + 2 * 194 * 194 * 32);  // 9*256*8 bf16

  int prep_threads = 2 * 194 * 194 * 4 + 9 * 4 * 64;
  k_prep<<<(prep_threads + 255) / 256, 256, 0, stream>>>(x, xp, conv_w, wf);
  k_main<<<2304, 256, 0, stream>>>(xp, p1w, p1b, (const s16x8*)wf, out);
}